// Round 10
// baseline (152.968 us; speedup 1.0000x reference)
//
#include <hip/hip_runtime.h>
#include <math.h>

#define HW 9216
#define C 64
#define BATCH 2
#define K 7
#define NCH 16
#define CHUNK 576            // HW/NCH
#define NOUT 9               // outer steps, 64 rows each
#define LTOP 8               // per-chunk kept candidates
#define NCAND 128            // NCH*LTOP
#define MB 8                 // m per output group
#define GPB 9                // groups per k_out block (2304 / 256)

typedef __attribute__((ext_vector_type(8))) short bf16x8;
typedef __attribute__((ext_vector_type(16))) float f32x16;

#define GLOAD_LDS(gp, lp) __builtin_amdgcn_global_load_lds( \
    (const __attribute__((address_space(1))) unsigned int*)(gp), \
    (__attribute__((address_space(3))) unsigned int*)(lp), 16, 0, 0)

__device__ __forceinline__ unsigned umax_(unsigned a, unsigned b) {
#if defined(__has_builtin) && __has_builtin(__builtin_elementwise_max)
    return __builtin_elementwise_max(a, b);
#else
    return a >= b ? a : b;
#endif
}
__device__ __forceinline__ unsigned umin_(unsigned a, unsigned b) {
#if defined(__has_builtin) && __has_builtin(__builtin_elementwise_min)
    return __builtin_elementwise_min(a, b);
#else
    return a >= b ? b : a;
#endif
}

// Batcher odd-even sort-8, descending, 19 CE
__device__ __forceinline__ void sort8_desc(unsigned (&k)[8]) {
#define CE8(i, j) { unsigned hi = umax_(k[i], k[j]); unsigned lo = umin_(k[i], k[j]); k[i] = hi; k[j] = lo; }
    CE8(0,1) CE8(2,3) CE8(4,5) CE8(6,7)
    CE8(0,2) CE8(1,3) CE8(4,6) CE8(5,7)
    CE8(1,2) CE8(5,6)
    CE8(0,4) CE8(1,5) CE8(2,6) CE8(3,7)
    CE8(2,4) CE8(3,5)
    CE8(1,2) CE8(3,4) CE8(5,6)
#undef CE8
}

// tv (sorted desc) := top-8 of tv ∪ s (s sorted desc), sorted desc.
__device__ __forceinline__ void merge8_desc(unsigned (&tv)[8], const unsigned (&s)[8]) {
    unsigned t[8];
#pragma unroll
    for (int i = 0; i < 8; ++i) t[i] = umax_(tv[i], s[7 - i]);
#define CET(i, j) { unsigned hi = umax_(t[i], t[j]); unsigned lo = umin_(t[i], t[j]); t[i] = hi; t[j] = lo; }
    CET(0,4) CET(1,5) CET(2,6) CET(3,7)
    CET(0,2) CET(1,3) CET(4,6) CET(5,7)
    CET(0,1) CET(2,3) CET(4,5) CET(6,7)
#undef CET
#pragma unroll
    for (int i = 0; i < 8; ++i) tv[i] = t[i];
}

// ---------------- kernel 1: normalize + transpose + bf16 (+ fused W transpose) ----------------
__global__ __launch_bounds__(256) void k_norm(const float* __restrict__ x,
                                              const float* __restrict__ W,
                                              float* __restrict__ XT,
                                              unsigned short* __restrict__ Xhi,
                                              float* __restrict__ invn,
                                              float* __restrict__ Wt) {
    int b = blockIdx.y, tid = threadIdx.x;
    int bx = blockIdx.x;
    if (bx >= HW / 64) {
        if (b == 0) {
            int base = (bx - HW / 64) * 1024 + tid * 4;
#pragma unroll
            for (int j = 0; j < 4; ++j) {
                int idx = base + j;
                int k = idx >> 12;
                int rem = idx & 4095;
                int i = rem >> 6, o = rem & 63;
                Wt[idx] = W[(o * C + i) * K + k];
            }
        }
        return;
    }
    int m0 = bx * 64;
    __shared__ float T[64 * 65];
    __shared__ float ps[4][64];
    __shared__ float inv[64];
    const float* xb = x + (size_t)b * C * HW;
    for (int r = 0; r < 16; ++r) {
        int idx = r * 256 + tid; int c = idx >> 6, mm = idx & 63;
        T[c * 65 + mm] = xb[(size_t)c * HW + m0 + mm];
    }
    __syncthreads();
    int ml = tid & 63, part = tid >> 6;
    float s = 0.f;
    for (int c = part * 16; c < part * 16 + 16; ++c) { float v = T[c * 65 + ml]; s += v * v; }
    ps[part][ml] = s;
    __syncthreads();
    if (tid < 64) {
        float tot = ps[0][tid] + ps[1][tid] + ps[2][tid] + ps[3][tid];
        float iv = 1.0f / sqrtf(tot);
        inv[tid] = iv;
        invn[(size_t)b * HW + m0 + tid] = iv;
    }
    __syncthreads();
    for (int r = 0; r < 16; ++r) {
        int idx = r * 256 + tid; int row = idx >> 6, c = idx & 63;
        float uv = T[c * 65 + row];
        XT[((size_t)b * HW + m0 + row) * C + c] = uv;
        float nv = uv * inv[row];
        unsigned u = __float_as_uint(nv);
        unsigned rr = u + 0x7fffu + ((u >> 16) & 1u);   // RNE to bf16
        Xhi[((size_t)b * HW + m0 + row) * C + c] = (unsigned short)(rr >> 16);
    }
}

// ---------------- kernel 2: MFMA approx scores + batch sort-merge top-8 ----------------
__global__ __launch_bounds__(256) void k_score(const unsigned short* __restrict__ Xhi,
                                               unsigned* __restrict__ candi) {
    int mg = blockIdx.x, chunk = blockIdx.y, b = blockIdx.z;
    int tid = threadIdx.x;
    int w = tid >> 6, l = tid & 63;
    int lr = l & 31, lh = l >> 5;
    int m = mg * 128 + w * 32 + lr;
    const char* Xb = (const char*)(Xhi + (size_t)b * HW * C);   // 128B rows

    __shared__ __align__(16) char tiles[2][8192];

    bf16x8 bf[4];
#pragma unroll
    for (int t = 0; t < 4; ++t)
        bf[t] = *(const bf16x8*)(Xb + (size_t)m * 128 + t * 32 + lh * 16);

    int swsrc = (tid * 16) ^ (((tid >> 3) & 7) << 4);   // within first 4KB
    int nC = chunk * CHUNK;

    GLOAD_LDS(Xb + (size_t)nC * 128 + swsrc, &tiles[0][w * 1024]);
    GLOAD_LDS(Xb + (size_t)nC * 128 + 4096 + swsrc, &tiles[0][4096 + w * 1024]);
    __syncthreads();

    unsigned tv[LTOP];
#pragma unroll
    for (int j = 0; j < LTOP; ++j) tv[j] = 0u;

    const float BIAS = 1.0625f;
    const f32x16 cbias = {BIAS,BIAS,BIAS,BIAS,BIAS,BIAS,BIAS,BIAS,
                          BIAS,BIAS,BIAS,BIAS,BIAS,BIAS,BIAS,BIAS};

    for (int so = 0; so < NOUT; ++so) {
        if (so + 1 < NOUT) {
            const char* src = Xb + (size_t)(nC + (so + 1) * 64) * 128;
            GLOAD_LDS(src + swsrc, &tiles[(so + 1) & 1][w * 1024]);
            GLOAD_LDS(src + 4096 + swsrc, &tiles[(so + 1) & 1][4096 + w * 1024]);
        }
        const char* tile = tiles[so & 1];
#pragma unroll
        for (int h = 0; h < 2; ++h) {
            bf16x8 af0 = *(const bf16x8*)(tile + (h * 32 + lr) * 128 + ((lh * 16) ^ ((lr & 7) << 4)));
            f32x16 acc = __builtin_amdgcn_mfma_f32_32x32x16_bf16(af0, bf[0], cbias, 0, 0, 0);
#pragma unroll
            for (int t = 1; t < 4; ++t) {
                int o = t * 32 + lh * 16;
                bf16x8 af = *(const bf16x8*)(tile + (h * 32 + lr) * 128 + (o ^ ((lr & 7) << 4)));
                acc = __builtin_amdgcn_mfma_f32_32x32x16_bf16(af, bf[t], acc, 0, 0, 0);
            }
            unsigned inv_base = 2047u - (unsigned)(so * 64 + h * 32 + 4 * lh);
            unsigned ka[8], kb[8];
#pragma unroll
            for (int r = 0; r < 8; ++r) {
                ka[r] = (__float_as_uint(acc[r]) & 0xFFFFF800u)
                      | (inv_base - (unsigned)((r & 3) + 8 * (r >> 2)));
                kb[r] = (__float_as_uint(acc[r + 8]) & 0xFFFFF800u)
                      | (inv_base - (unsigned)(((r + 8) & 3) + 8 * ((r + 8) >> 2)));
            }
            sort8_desc(ka);
            sort8_desc(kb);
            merge8_desc(tv, ka);
            merge8_desc(tv, kb);
        }
        __syncthreads();
    }

    // bitonic partial merge with partner half-lane
    unsigned pv[LTOP];
#pragma unroll
    for (int j = 0; j < LTOP; ++j) pv[j] = tv[j];
#pragma unroll
    for (int j = 0; j < LTOP; ++j) {
        unsigned o = (unsigned)__shfl_xor((int)pv[LTOP - 1 - j], 32, 64);
        tv[j] = umax_(tv[j], o);
    }
    if (lh == 0) {
        size_t base = ((size_t)(b * HW + m) * NCH + chunk) * LTOP;
#pragma unroll
        for (int j = 0; j < LTOP; ++j) candi[base + j] = tv[j];
    }
}

// ---------------- kernel 3: threshold-pruned exact fp32 rescore ----------------
__global__ __launch_bounds__(256) void k_rescore(const float* __restrict__ XT,
                                                 const float* __restrict__ invn,
                                                 const unsigned* __restrict__ candi,
                                                 float* __restrict__ fvals,
                                                 int* __restrict__ fidx) {
    int g = blockIdx.x * 4 + (threadIdx.x >> 6);
    int l = threadIdx.x & 63;
    int b = g / HW, m = g - b * HW;
    const float* Xb = XT + (size_t)b * HW * C;
    float xml = Xb[(size_t)m * C + l];
    float vm = invn[g];

    unsigned k0 = candi[(size_t)g * NCAND + l];
    unsigned k1 = candi[(size_t)g * NCAND + 64 + l];

    // radix binary search: largest 21-bit score prefix T with count(key >= T) >= 7
    unsigned thr = 0u;
#pragma unroll
    for (int bit = 30; bit >= 11; --bit) {    // scores < 4.0 -> bit31 always 0
        unsigned cand = thr | (1u << bit);
        int cnt = __popcll(__ballot(k0 >= cand)) + __popcll(__ballot(k1 >= cand));
        if (cnt >= 7) thr = cand;
    }
    float s7 = __uint_as_float(thr);
    unsigned thk = __float_as_uint(s7 - 0.012f) & 0xFFFFF800u;

    unsigned long long bal0 = __ballot(k0 >= thk);
    unsigned long long bal1 = __ballot(k1 >= thk);

    float svv = -1e30f; int svi = 0x7fffffff;
    int nsurv = 0;
#pragma unroll
    for (int h = 0; h < 2; ++h) {
        unsigned long long bb = h ? bal1 : bal0;
        while (bb) {
            int src = __builtin_ctzll(bb);
            bb &= bb - 1;
            unsigned key = (unsigned)__shfl((int)(h ? k1 : k0), src, 64);
            int cpos = h * 64 + src;
            int ci = (cpos >> 3) * CHUNK + (2047 - (int)(key & 0x7FFu));
            float v = xml * Xb[(size_t)ci * C + l];
            v += __shfl_xor(v, 1, 64);  v += __shfl_xor(v, 2, 64);
            v += __shfl_xor(v, 4, 64);  v += __shfl_xor(v, 8, 64);
            v += __shfl_xor(v, 16, 64); v += __shfl_xor(v, 32, 64);
            if (l == nsurv) { svv = v * vm * invn[(size_t)b * HW + ci]; svi = ci; }
            ++nsurv;
        }
    }

    for (int s = 0; s < 7; ++s) {
        float bv = svv; int bi = svi;
#pragma unroll
        for (int d = 1; d < 64; d <<= 1) {
            float ov = __shfl_xor(bv, d, 64);
            int   oi = __shfl_xor(bi, d, 64);
            if (ov > bv || (ov == bv && oi < bi)) { bv = ov; bi = oi; }
        }
        if (l == 0) { fvals[(size_t)g * 7 + s] = bv; fidx[(size_t)g * 7 + s] = bi; }
        if (svi == bi) svv = -1e30f;
    }
}

// ---------------- kernel 4: W-in-LDS gather + conv + bias + relu, 9 groups/block ----------------
// grid = 256 blocks (1/CU); W staged to LDS once; gather register-prefetched per group.
__global__ __launch_bounds__(256) void k_out(const float* __restrict__ XT,
                                             const float* __restrict__ Wt,
                                             const float* __restrict__ fvals,
                                             const int* __restrict__ fidx,
                                             const float* __restrict__ bias,
                                             float* __restrict__ out) {
    __shared__ float Wl[K * C * C];       // 112 KB  [k][i][o]
    __shared__ float Gw[2][K][MB][68];    // 30.5 KB (double-buffered)
    __shared__ float Red[4][MB][68];      // 8.7 KB
    int tid = threadIdx.x;

    // stage W to LDS: 7168 float4, coalesced
#pragma unroll
    for (int r = 0; r < 28; ++r) {
        int e4 = r * 256 + tid;
        *(float4*)&Wl[e4 * 4] = *(const float4*)&Wt[e4 * 4];
    }

    int g0 = blockIdx.x * GPB;

    // prefetch group 0 gathers into registers
    float4 gr[4]; float gv[4];
    {
        int gg = g0;
        int b = gg / (HW / MB), m0 = (gg % (HW / MB)) * MB;
#pragma unroll
        for (int t = 0; t < 4; ++t) {
            int slot = t * 256 + tid;
            if (slot < K * MB * 16) {
                int k = slot >> 7, rem = slot & 127, m2 = rem >> 4, i4 = rem & 15;
                int gm = (b * HW + m0 + m2) * 7 + k;
                int n = fidx[gm];
                gv[t] = fvals[gm];
                gr[t] = *(const float4*)&XT[((size_t)b * HW + n) * C + i4 * 4];
            }
        }
    }
    __syncthreads();   // W staged

    for (int j = 0; j < GPB; ++j) {
        int gg = g0 + j;
        int b = gg / (HW / MB), m0 = (gg % (HW / MB)) * MB;
        int buf = j & 1;

        // write staged gather regs -> Gw[buf]
#pragma unroll
        for (int t = 0; t < 4; ++t) {
            int slot = t * 256 + tid;
            if (slot < K * MB * 16) {
                int k = slot >> 7, rem = slot & 127, m2 = rem >> 4, i4 = rem & 15;
                float4 g = gr[t]; float vv = gv[t];
                float4 gw = {g.x * vv, g.y * vv, g.z * vv, g.w * vv};
                *(float4*)&Gw[buf][k][m2][i4 * 4] = gw;
            }
        }
        __syncthreads();   // Gw[buf] ready (and all prior phase-2 reads done)

        // prefetch group j+1 (hidden under compute below)
        if (j + 1 < GPB) {
            int gg2 = gg + 1;
            int b2 = gg2 / (HW / MB), m02 = (gg2 % (HW / MB)) * MB;
#pragma unroll
            for (int t = 0; t < 4; ++t) {
                int slot = t * 256 + tid;
                if (slot < K * MB * 16) {
                    int k = slot >> 7, rem = slot & 127, m2 = rem >> 4, i4 = rem & 15;
                    int gm = (b2 * HW + m02 + m2) * 7 + k;
                    int n = fidx[gm];
                    gv[t] = fvals[gm];
                    gr[t] = *(const float4*)&XT[((size_t)b2 * HW + n) * C + i4 * 4];
                }
            }
        }

        // phase 2: thread (oq, sub) over i in [sub*4, sub*4+4), all k; W from LDS
        int oq = tid & 15, sub = tid >> 4;
        float acc[MB][4] = {};
#pragma unroll
        for (int k = 0; k < K; ++k) {
#pragma unroll
            for (int jj = 0; jj < 4; ++jj) {
                int i = sub * 4 + jj;
                float4 w4 = *(const float4*)&Wl[(k * C + i) * C + oq * 4];
#pragma unroll
                for (int m = 0; m < MB; ++m) {
                    float g = Gw[buf][k][m][i];
                    acc[m][0] += g * w4.x; acc[m][1] += g * w4.y;
                    acc[m][2] += g * w4.z; acc[m][3] += g * w4.w;
                }
            }
        }

        // phase 3a: reduce across the wave's 4 subs
#pragma unroll
        for (int m = 0; m < MB; ++m)
#pragma unroll
            for (int q = 0; q < 4; ++q) {
                acc[m][q] += __shfl_xor(acc[m][q], 16, 64);
                acc[m][q] += __shfl_xor(acc[m][q], 32, 64);
            }
        int w = tid >> 6, l = tid & 63;
        if (l < 16) {
#pragma unroll
            for (int m = 0; m < MB; ++m) {
                float4 r4 = {acc[m][0], acc[m][1], acc[m][2], acc[m][3]};
                *(float4*)&Red[w][m][l * 4] = r4;
            }
        }
        __syncthreads();   // Red ready

        // phase 3b: final sum over 4 waves + bias + relu
#pragma unroll
        for (int t2 = 0; t2 < 2; ++t2) {
            int oidx = t2 * 256 + tid;             // 512 = 8m x 64o
            int m = oidx & 7, o = oidx >> 3;
            float v = Red[0][m][o] + Red[1][m][o] + Red[2][m][o] + Red[3][m][o] + bias[o];
            out[((size_t)b * C + o) * HW + m0 + m] = v > 0.f ? v : 0.f;
        }
        // no barrier needed: next iter writes Gw[buf^1]; Red rewrite is after next barrier
    }
}

extern "C" void kernel_launch(void* const* d_in, const int* in_sizes, int n_in,
                              void* d_out, int out_size, void* d_ws, size_t ws_size,
                              hipStream_t stream) {
    const float* x = (const float*)d_in[0];
    const float* W = (const float*)d_in[1];
    const float* bias = (const float*)d_in[2];
    float* out = (float*)d_out;

    float* ws = (float*)d_ws;
    float* XT = ws;                                        // B*HW*C f32
    unsigned short* Xhi = (unsigned short*)(XT + (size_t)BATCH * HW * C);   // B*HW*C bf16
    float* invn = (float*)(Xhi + (size_t)BATCH * HW * C);  // B*HW
    float* Wt = invn + (size_t)BATCH * HW;                 // K*C*C
    unsigned* candi = (unsigned*)(Wt + C * C * K);         // B*HW*NCAND packed keys
    float* fvals = (float*)(candi + (size_t)BATCH * HW * NCAND);
    int* fidx = (int*)(fvals + (size_t)BATCH * HW * K);

    k_norm<<<dim3(HW / 64 + 28, BATCH), 256, 0, stream>>>(x, W, XT, Xhi, invn, Wt);
    k_score<<<dim3(HW / 128, NCH, BATCH), 256, 0, stream>>>(Xhi, candi);
    k_rescore<<<dim3(BATCH * HW / 4), 256, 0, stream>>>(XT, invn, candi, fvals, fidx);
    k_out<<<dim3(BATCH * HW / MB / GPB), 256, 0, stream>>>(XT, Wt, fvals, fidx, bias, out);
}

// Round 11
// 123.944 us; speedup vs baseline: 1.2342x; 1.2342x over previous
//
#include <hip/hip_runtime.h>
#include <math.h>

#define HW 9216
#define C 64
#define BATCH 2
#define K 7
#define NCH 16
#define CHUNK 576            // HW/NCH
#define NOUT 9               // outer steps, 64 rows each
#define LTOP 8               // per-chunk kept candidates
#define NCAND 128            // NCH*LTOP
#define IK 448               // K*C contraction length
#define GA_STRIDE 456        // IK + 8 (stride in bf16; 228 words ≡ 4 mod 32)

typedef __attribute__((ext_vector_type(8))) short bf16x8;
typedef __attribute__((ext_vector_type(16))) float f32x16;

#define GLOAD_LDS(gp, lp) __builtin_amdgcn_global_load_lds( \
    (const __attribute__((address_space(1))) unsigned int*)(gp), \
    (__attribute__((address_space(3))) unsigned int*)(lp), 16, 0, 0)

__device__ __forceinline__ unsigned umax_(unsigned a, unsigned b) {
#if defined(__has_builtin) && __has_builtin(__builtin_elementwise_max)
    return __builtin_elementwise_max(a, b);
#else
    return a >= b ? a : b;
#endif
}
__device__ __forceinline__ unsigned umin_(unsigned a, unsigned b) {
#if defined(__has_builtin) && __has_builtin(__builtin_elementwise_min)
    return __builtin_elementwise_min(a, b);
#else
    return a >= b ? b : a;
#endif
}

__device__ __forceinline__ unsigned short rne_bf16(float f) {
    unsigned u = __float_as_uint(f);
    unsigned r = u + 0x7fffu + ((u >> 16) & 1u);
    return (unsigned short)(r >> 16);
}

// Batcher odd-even sort-8, descending, 19 CE
__device__ __forceinline__ void sort8_desc(unsigned (&k)[8]) {
#define CE8(i, j) { unsigned hi = umax_(k[i], k[j]); unsigned lo = umin_(k[i], k[j]); k[i] = hi; k[j] = lo; }
    CE8(0,1) CE8(2,3) CE8(4,5) CE8(6,7)
    CE8(0,2) CE8(1,3) CE8(4,6) CE8(5,7)
    CE8(1,2) CE8(5,6)
    CE8(0,4) CE8(1,5) CE8(2,6) CE8(3,7)
    CE8(2,4) CE8(3,5)
    CE8(1,2) CE8(3,4) CE8(5,6)
#undef CE8
}

// tv (sorted desc) := top-8 of tv ∪ s (s sorted desc), sorted desc.
__device__ __forceinline__ void merge8_desc(unsigned (&tv)[8], const unsigned (&s)[8]) {
    unsigned t[8];
#pragma unroll
    for (int i = 0; i < 8; ++i) t[i] = umax_(tv[i], s[7 - i]);
#define CET(i, j) { unsigned hi = umax_(t[i], t[j]); unsigned lo = umin_(t[i], t[j]); t[i] = hi; t[j] = lo; }
    CET(0,4) CET(1,5) CET(2,6) CET(3,7)
    CET(0,2) CET(1,3) CET(4,6) CET(5,7)
    CET(0,1) CET(2,3) CET(4,5) CET(6,7)
#undef CET
#pragma unroll
    for (int i = 0; i < 8; ++i) tv[i] = t[i];
}

// ---------------- kernel 1: normalize + transpose + bf16 (+ fused W->bf16 transpose) ----------------
__global__ __launch_bounds__(256) void k_norm(const float* __restrict__ x,
                                              const float* __restrict__ W,
                                              float* __restrict__ XT,
                                              unsigned short* __restrict__ Xhi,
                                              float* __restrict__ invn,
                                              unsigned short* __restrict__ WbT) {
    int b = blockIdx.y, tid = threadIdx.x;
    int bx = blockIdx.x;
    if (bx >= HW / 64) {
        // WbT[o][kq*64 + i] = bf16(W[(o*C + i)*K + kq]); 28672 elems over 28 blocks
        if (b == 0) {
            int base = (bx - HW / 64) * 1024 + tid * 4;
#pragma unroll
            for (int j = 0; j < 4; ++j) {
                int idx = base + j;
                int o = idx / IK;
                int rem = idx - o * IK;
                int kq = rem >> 6, i = rem & 63;
                WbT[idx] = rne_bf16(W[(o * C + i) * K + kq]);
            }
        }
        return;
    }
    int m0 = bx * 64;
    __shared__ float T[64 * 65];
    __shared__ float ps[4][64];
    __shared__ float inv[64];
    const float* xb = x + (size_t)b * C * HW;
    for (int r = 0; r < 16; ++r) {
        int idx = r * 256 + tid; int c = idx >> 6, mm = idx & 63;
        T[c * 65 + mm] = xb[(size_t)c * HW + m0 + mm];
    }
    __syncthreads();
    int ml = tid & 63, part = tid >> 6;
    float s = 0.f;
    for (int c = part * 16; c < part * 16 + 16; ++c) { float v = T[c * 65 + ml]; s += v * v; }
    ps[part][ml] = s;
    __syncthreads();
    if (tid < 64) {
        float tot = ps[0][tid] + ps[1][tid] + ps[2][tid] + ps[3][tid];
        float iv = 1.0f / sqrtf(tot);
        inv[tid] = iv;
        invn[(size_t)b * HW + m0 + tid] = iv;
    }
    __syncthreads();
    for (int r = 0; r < 16; ++r) {
        int idx = r * 256 + tid; int row = idx >> 6, c = idx & 63;
        float uv = T[c * 65 + row];
        XT[((size_t)b * HW + m0 + row) * C + c] = uv;
        Xhi[((size_t)b * HW + m0 + row) * C + c] = rne_bf16(uv * inv[row]);
    }
}

// ---------------- kernel 2: MFMA approx scores + batch sort-merge top-8 ----------------
__global__ __launch_bounds__(256) void k_score(const unsigned short* __restrict__ Xhi,
                                               unsigned* __restrict__ candi) {
    int mg = blockIdx.x, chunk = blockIdx.y, b = blockIdx.z;
    int tid = threadIdx.x;
    int w = tid >> 6, l = tid & 63;
    int lr = l & 31, lh = l >> 5;
    int m = mg * 128 + w * 32 + lr;
    const char* Xb = (const char*)(Xhi + (size_t)b * HW * C);   // 128B rows

    __shared__ __align__(16) char tiles[2][8192];

    bf16x8 bf[4];
#pragma unroll
    for (int t = 0; t < 4; ++t)
        bf[t] = *(const bf16x8*)(Xb + (size_t)m * 128 + t * 32 + lh * 16);

    int swsrc = (tid * 16) ^ (((tid >> 3) & 7) << 4);   // within first 4KB
    int nC = chunk * CHUNK;

    GLOAD_LDS(Xb + (size_t)nC * 128 + swsrc, &tiles[0][w * 1024]);
    GLOAD_LDS(Xb + (size_t)nC * 128 + 4096 + swsrc, &tiles[0][4096 + w * 1024]);
    __syncthreads();

    unsigned tv[LTOP];
#pragma unroll
    for (int j = 0; j < LTOP; ++j) tv[j] = 0u;

    const float BIAS = 1.0625f;
    const f32x16 cbias = {BIAS,BIAS,BIAS,BIAS,BIAS,BIAS,BIAS,BIAS,
                          BIAS,BIAS,BIAS,BIAS,BIAS,BIAS,BIAS,BIAS};

    for (int so = 0; so < NOUT; ++so) {
        if (so + 1 < NOUT) {
            const char* src = Xb + (size_t)(nC + (so + 1) * 64) * 128;
            GLOAD_LDS(src + swsrc, &tiles[(so + 1) & 1][w * 1024]);
            GLOAD_LDS(src + 4096 + swsrc, &tiles[(so + 1) & 1][4096 + w * 1024]);
        }
        const char* tile = tiles[so & 1];
#pragma unroll
        for (int h = 0; h < 2; ++h) {
            bf16x8 af0 = *(const bf16x8*)(tile + (h * 32 + lr) * 128 + ((lh * 16) ^ ((lr & 7) << 4)));
            f32x16 acc = __builtin_amdgcn_mfma_f32_32x32x16_bf16(af0, bf[0], cbias, 0, 0, 0);
#pragma unroll
            for (int t = 1; t < 4; ++t) {
                int o = t * 32 + lh * 16;
                bf16x8 af = *(const bf16x8*)(tile + (h * 32 + lr) * 128 + (o ^ ((lr & 7) << 4)));
                acc = __builtin_amdgcn_mfma_f32_32x32x16_bf16(af, bf[t], acc, 0, 0, 0);
            }
            unsigned inv_base = 2047u - (unsigned)(so * 64 + h * 32 + 4 * lh);
            unsigned ka[8], kb[8];
#pragma unroll
            for (int r = 0; r < 8; ++r) {
                ka[r] = (__float_as_uint(acc[r]) & 0xFFFFF800u)
                      | (inv_base - (unsigned)((r & 3) + 8 * (r >> 2)));
                kb[r] = (__float_as_uint(acc[r + 8]) & 0xFFFFF800u)
                      | (inv_base - (unsigned)(((r + 8) & 3) + 8 * ((r + 8) >> 2)));
            }
            sort8_desc(ka);
            sort8_desc(kb);
            merge8_desc(tv, ka);
            merge8_desc(tv, kb);
        }
        __syncthreads();
    }

    // bitonic partial merge with partner half-lane
    unsigned pv[LTOP];
#pragma unroll
    for (int j = 0; j < LTOP; ++j) pv[j] = tv[j];
#pragma unroll
    for (int j = 0; j < LTOP; ++j) {
        unsigned o = (unsigned)__shfl_xor((int)pv[LTOP - 1 - j], 32, 64);
        tv[j] = umax_(tv[j], o);
    }
    if (lh == 0) {
        size_t base = ((size_t)(b * HW + m) * NCH + chunk) * LTOP;
#pragma unroll
        for (int j = 0; j < LTOP; ++j) candi[base + j] = tv[j];
    }
}

// ---------------- kernel 3: threshold-pruned exact fp32 rescore ----------------
__global__ __launch_bounds__(256) void k_rescore(const float* __restrict__ XT,
                                                 const float* __restrict__ invn,
                                                 const unsigned* __restrict__ candi,
                                                 float* __restrict__ fvals,
                                                 int* __restrict__ fidx) {
    int g = blockIdx.x * 4 + (threadIdx.x >> 6);
    int l = threadIdx.x & 63;
    int b = g / HW, m = g - b * HW;
    const float* Xb = XT + (size_t)b * HW * C;
    float xml = Xb[(size_t)m * C + l];
    float vm = invn[g];

    unsigned k0 = candi[(size_t)g * NCAND + l];
    unsigned k1 = candi[(size_t)g * NCAND + 64 + l];

    // radix binary search: largest 21-bit score prefix T with count(key >= T) >= 7
    unsigned thr = 0u;
#pragma unroll
    for (int bit = 30; bit >= 11; --bit) {    // scores < 4.0 -> bit31 always 0
        unsigned cand = thr | (1u << bit);
        int cnt = __popcll(__ballot(k0 >= cand)) + __popcll(__ballot(k1 >= cand));
        if (cnt >= 7) thr = cand;
    }
    float s7 = __uint_as_float(thr);
    unsigned thk = __float_as_uint(s7 - 0.012f) & 0xFFFFF800u;

    unsigned long long bal0 = __ballot(k0 >= thk);
    unsigned long long bal1 = __ballot(k1 >= thk);

    float svv = -1e30f; int svi = 0x7fffffff;
    int nsurv = 0;
#pragma unroll
    for (int h = 0; h < 2; ++h) {
        unsigned long long bb = h ? bal1 : bal0;
        while (bb) {
            int src = __builtin_ctzll(bb);
            bb &= bb - 1;
            unsigned key = (unsigned)__shfl((int)(h ? k1 : k0), src, 64);
            int cpos = h * 64 + src;
            int ci = (cpos >> 3) * CHUNK + (2047 - (int)(key & 0x7FFu));
            float v = xml * Xb[(size_t)ci * C + l];
            v += __shfl_xor(v, 1, 64);  v += __shfl_xor(v, 2, 64);
            v += __shfl_xor(v, 4, 64);  v += __shfl_xor(v, 8, 64);
            v += __shfl_xor(v, 16, 64); v += __shfl_xor(v, 32, 64);
            if (l == nsurv) { svv = v * vm * invn[(size_t)b * HW + ci]; svi = ci; }
            ++nsurv;
        }
    }

    for (int s = 0; s < 7; ++s) {
        float bv = svv; int bi = svi;
#pragma unroll
        for (int d = 1; d < 64; d <<= 1) {
            float ov = __shfl_xor(bv, d, 64);
            int   oi = __shfl_xor(bi, d, 64);
            if (ov > bv || (ov == bv && oi < bi)) { bv = ov; bi = oi; }
        }
        if (l == 0) { fvals[(size_t)g * 7 + s] = bv; fidx[(size_t)g * 7 + s] = bi; }
        if (svi == bi) svv = -1e30f;
    }
}

// ---------------- kernel 4: bf16-MFMA conv: gather->LDS, D = Ga(64x448) x WbT^T(448x64) ----------------
// grid (HW/64, BATCH); 4 waves = 2 m-tiles x 2 o-tiles; bias in accumulator; coalesced epilogue.
__global__ __launch_bounds__(256) void k_out(const float* __restrict__ XT,
                                             const unsigned short* __restrict__ WbT,
                                             const float* __restrict__ fvals,
                                             const int* __restrict__ fidx,
                                             const float* __restrict__ bias,
                                             float* __restrict__ out) {
    int b = blockIdx.y;
    int m0 = blockIdx.x * 64;
    int tid = threadIdx.x;
    int w = tid >> 6, l = tid & 63;
    int lr = l & 31, hi = l >> 5;

    __shared__ __align__(16) unsigned short Ga[64][GA_STRIDE];  // 58.4 KB, bf16 [m][ik]
    __shared__ float Red[64][68];                               // 17.4 KB  [o][m]
    __shared__ int   fiL[64 * K];
    __shared__ float fvL[64 * K];

    // load the 448 (m,k) gather descriptors
#pragma unroll
    for (int t = 0; t < 2; ++t) {
        int idx = t * 256 + tid;
        if (idx < 64 * K) {
            int gm = (b * HW + m0 + (idx / K)) * K + (idx % K);
            fiL[idx] = fidx[gm];
            fvL[idx] = fvals[gm];
        }
    }
    __syncthreads();

    // gather + scale + bf16 -> Ga ; 448 rows x 16 slots, coalesced float4 reads
#pragma unroll
    for (int t = 0; t < 28; ++t) {
        int slot = t * 256 + tid;              // 7168 slots
        int r = slot >> 4, i4 = slot & 15;     // r = kq*64 + m
        int m = r & 63, kq = r >> 6;
        int n = fiL[m * K + kq];
        float vv = fvL[m * K + kq];
        float4 g = *(const float4*)&XT[((size_t)b * HW + n) * C + i4 * 4];
        unsigned short h0 = rne_bf16(g.x * vv), h1 = rne_bf16(g.y * vv);
        unsigned short h2 = rne_bf16(g.z * vv), h3 = rne_bf16(g.w * vv);
        unsigned p0 = (unsigned)h0 | ((unsigned)h1 << 16);
        unsigned p1 = (unsigned)h2 | ((unsigned)h3 << 16);
        uint2 p = {p0, p1};
        *(uint2*)&Ga[m][kq * 64 + i4 * 4] = p;
    }
    __syncthreads();

    // MFMA: wave w -> m-tile (w&1), o-tile (w>>1); 28 steps over ik
    int mt = w & 1, ct = w >> 1;
    int arow = mt * 32 + lr;
    int ocol = ct * 32 + lr;
    float bv = bias[ocol];
    f32x16 acc;
#pragma unroll
    for (int r = 0; r < 16; ++r) acc[r] = bv;

    const unsigned short* wrow = WbT + (size_t)ocol * IK;
#pragma unroll
    for (int s = 0; s < 28; ++s) {
        bf16x8 af = *(const bf16x8*)&Ga[arow][s * 16 + hi * 8];
        bf16x8 bf = *(const bf16x8*)&wrow[s * 16 + hi * 8];
        acc = __builtin_amdgcn_mfma_f32_32x32x16_bf16(af, bf, acc, 0, 0, 0);
    }

    // write acc -> Red[o][m] (4x float4 per lane: rows 4*hi + {0..3} + 8*j)
#pragma unroll
    for (int j = 0; j < 4; ++j) {
        float4 r4 = {acc[j * 4 + 0], acc[j * 4 + 1], acc[j * 4 + 2], acc[j * 4 + 3]};
        *(float4*)&Red[ocol][mt * 32 + j * 8 + hi * 4] = r4;
    }
    __syncthreads();

    // coalesced store: 4096 floats = 64 o x 64 m, relu
#pragma unroll
    for (int t = 0; t < 4; ++t) {
        int slot4 = t * 256 + tid;             // 1024 float4
        int o = slot4 >> 4, m4 = slot4 & 15;
        float4 v = *(const float4*)&Red[o][m4 * 4];
        v.x = v.x > 0.f ? v.x : 0.f;
        v.y = v.y > 0.f ? v.y : 0.f;
        v.z = v.z > 0.f ? v.z : 0.f;
        v.w = v.w > 0.f ? v.w : 0.f;
        *(float4*)&out[((size_t)b * C + o) * HW + m0 + m4 * 4] = v;
    }
}

extern "C" void kernel_launch(void* const* d_in, const int* in_sizes, int n_in,
                              void* d_out, int out_size, void* d_ws, size_t ws_size,
                              hipStream_t stream) {
    const float* x = (const float*)d_in[0];
    const float* W = (const float*)d_in[1];
    const float* bias = (const float*)d_in[2];
    float* out = (float*)d_out;

    float* ws = (float*)d_ws;
    float* XT = ws;                                        // B*HW*C f32
    unsigned short* Xhi = (unsigned short*)(XT + (size_t)BATCH * HW * C);   // B*HW*C bf16
    float* invn = (float*)(Xhi + (size_t)BATCH * HW * C);  // B*HW
    unsigned short* WbT = (unsigned short*)(invn + (size_t)BATCH * HW);     // 64*448 bf16
    unsigned* candi = (unsigned*)(WbT + (size_t)C * IK + 64);               // B*HW*NCAND
    float* fvals = (float*)(candi + (size_t)BATCH * HW * NCAND);
    int* fidx = (int*)(fvals + (size_t)BATCH * HW * K);

    k_norm<<<dim3(HW / 64 + 28, BATCH), 256, 0, stream>>>(x, W, XT, Xhi, invn, WbT);
    k_score<<<dim3(HW / 128, NCH, BATCH), 256, 0, stream>>>(Xhi, candi);
    k_rescore<<<dim3(BATCH * HW / 4), 256, 0, stream>>>(XT, invn, candi, fvals, fidx);
    k_out<<<dim3(HW / 64, BATCH), 256, 0, stream>>>(XT, WbT, fvals, fidx, bias, out);
}